// Round 3
// baseline (910.749 us; speedup 1.0000x reference)
//
#include <hip/hip_runtime.h>
#include <hip/hip_bf16.h>

// FlashAttention fwd: B=4,H=12,S=4096,D=64 fp32. Reference semantics incl. the
// extra cur_scale factor, folded in log2-domain: p = exp2(s' + cm' - 2*mn')
// where s' = s*log2(e) (log2e folded into Q scale).
// Pre-pass converts K -> bf16 [h][s][d] and V -> bf16 transposed [h][d][s]
// (with the PV k-slot permutation baked into column order) in d_ws.

#define S_LEN 4096
#define HD    64
#define QTILE 128
#define KTILE 128
#define NKT   32
#define NHEAD 48

#define KSTR  72                    // u16 stride of K_lds rows (144 B)
#define VSTR  136                   // u16 stride of Vt rows (272 B)
#define VT_OFF (128 * KSTR)         // 9216 u16
#define SMEM_U16 (VT_OFF + HD * VSTR)  // 17920 u16 = 35840 B
#define OSTR  68                    // epilogue float stride

#define WS_ELEMS ((size_t)NHEAD * S_LEN * HD)   // 12,582,912 per tensor

typedef __attribute__((ext_vector_type(8))) short bf16x8;
typedef __attribute__((ext_vector_type(4))) float f32x4;

// RNE f32->bf16 pair packed into u32 (pre-pass / Q only)
__device__ __forceinline__ unsigned int pk2(float f0, float f1) {
    unsigned int u0 = __builtin_bit_cast(unsigned int, f0);
    unsigned int u1 = __builtin_bit_cast(unsigned int, f1);
    u0 += 0x7FFFu + ((u0 >> 16) & 1u);
    u1 += 0x7FFFu + ((u1 >> 16) & 1u);
    return __builtin_amdgcn_perm(u1, u0, 0x07060302u);
}
// truncating pack (hot path, P only): 1 instr
__device__ __forceinline__ unsigned int pkt(float f0, float f1) {
    return __builtin_amdgcn_perm(__builtin_bit_cast(unsigned int, f1),
                                 __builtin_bit_cast(unsigned int, f0),
                                 0x07060302u);
}
__device__ __forceinline__ float e2(float x) {
#if __has_builtin(__builtin_amdgcn_exp2f)
    return __builtin_amdgcn_exp2f(x);
#else
    return __expf(x * 0.6931471805599453f);
#endif
}

// ---------------- pre-pass: K fp32 -> bf16, same layout ----------------
__global__ __launch_bounds__(256)
void k_convert(const float* __restrict__ K, unsigned short* __restrict__ Wk) {
    size_t idx = ((size_t)blockIdx.x * 256 + threadIdx.x) * 8;
    float4 a = *(const float4*)(K + idx);
    float4 b = *(const float4*)(K + idx + 4);
    union { unsigned int u[4]; bf16x8 v; } cv;
    cv.u[0] = pk2(a.x, a.y); cv.u[1] = pk2(a.z, a.w);
    cv.u[2] = pk2(b.x, b.y); cv.u[3] = pk2(b.z, b.w);
    *(bf16x8*)((unsigned short*)Wk + idx) = cv.v;
}

// ---- pre-pass: V fp32 [h][s][d] -> bf16 [h][d][s], cols permuted -------
// within each 128-col tile: position 32c+8q+4h8+r holds key 32c+16h8+4q+r
__global__ __launch_bounds__(256)
void v_trans(const float* __restrict__ V, unsigned short* __restrict__ Wv) {
    __shared__ unsigned short T[64 * 132];
    const int t = threadIdx.x;
    const int kt = blockIdx.x, head = blockIdx.y;
    const float* vp = V + (size_t)head * S_LEN * HD + (size_t)kt * KTILE * HD;
    const int d0 = (t & 15) * 4;
    const int kr = t >> 4;
    #pragma unroll
    for (int i = 0; i < 8; ++i) {
        int key = i * 16 + kr;
        float4 f = *(const float4*)(vp + key * HD + d0);
        unsigned int p01 = pk2(f.x, f.y), p23 = pk2(f.z, f.w);
        T[(d0 + 0) * 132 + key] = (unsigned short)(p01 & 0xffff);
        T[(d0 + 1) * 132 + key] = (unsigned short)(p01 >> 16);
        T[(d0 + 2) * 132 + key] = (unsigned short)(p23 & 0xffff);
        T[(d0 + 3) * 132 + key] = (unsigned short)(p23 >> 16);
    }
    __syncthreads();
    const int d = t >> 2;
    const int c = t & 3;
    unsigned short* op = Wv + (size_t)head * HD * S_LEN + (size_t)d * S_LEN
                         + kt * KTILE + c * 32;
    unsigned int out[16];
    #pragma unroll
    for (int jj = 0; jj < 16; ++jj) {
        int j0 = 2 * jj, j1 = 2 * jj + 1;
        int k0 = c * 32 + ((j0 >> 2) & 1) * 16 + (j0 >> 3) * 4 + (j0 & 3);
        int k1 = c * 32 + ((j1 >> 2) & 1) * 16 + (j1 >> 3) * 4 + (j1 & 3);
        out[jj] = (unsigned int)T[d * 132 + k0]
                | ((unsigned int)T[d * 132 + k1] << 16);
    }
    #pragma unroll
    for (int s = 0; s < 4; ++s)
        *(bf16x8*)(op + s * 8) = *(const bf16x8*)&out[s * 4];
}

// ---------------------------- main kernel ------------------------------
__global__ __launch_bounds__(256, 4)
void fattn_fast(const float* __restrict__ Q,
                const unsigned short* __restrict__ Wk,
                const unsigned short* __restrict__ Wv,
                float* __restrict__ O) {
    __shared__ __align__(16) unsigned short smem[SMEM_U16];

    const int t    = threadIdx.x;
    const int wave = t >> 6;
    const int lane = t & 63;
    const int m    = lane & 15;
    const int quad = lane >> 4;

    const int qblk = blockIdx.x;
    const int head = blockIdx.y;
    const size_t hbase = (size_t)head * S_LEN * HD;

    unsigned short* const Kl = smem;
    unsigned short* const Vt = smem + VT_OFF;

    // Q B-frags; scale = 0.125 * log2(e) folded (log2-domain scores)
    bf16x8 qf[2][2];
    #pragma unroll
    for (int rt = 0; rt < 2; ++rt) {
        const float* qp = Q + hbase +
            (size_t)(qblk * QTILE + wave * 32 + rt * 16 + m) * HD + quad * 8;
        #pragma unroll
        for (int kd = 0; kd < 2; ++kd) {
            float4 a = *(const float4*)(qp + kd * 32);
            float4 b = *(const float4*)(qp + kd * 32 + 4);
            union { unsigned int u[4]; bf16x8 v; } cv;
            const float s = 0.1803368801111f;   // 0.125 * log2(e)
            cv.u[0] = pk2(a.x * s, a.y * s);
            cv.u[1] = pk2(a.z * s, a.w * s);
            cv.u[2] = pk2(b.x * s, b.y * s);
            cv.u[3] = pk2(b.z * s, b.w * s);
            qf[rt][kd] = cv.v;
        }
    }

    f32x4 oacc[4][2];
    float mrow[2] = {-INFINITY, -INFINITY};
    float lrow[2] = {0.f, 0.f};
    #pragma unroll
    for (int dt = 0; dt < 4; ++dt)
        #pragma unroll
        for (int rt = 0; rt < 2; ++rt) oacc[dt][rt] = (f32x4){0.f,0.f,0.f,0.f};

    const int r0k = t >> 3;
    const int kch = t & 7;
    const int chk = ((t & 7) + ((t >> 3) & 7)) & 7;   // swizzled chunk pos
    const unsigned short* const kbase = Wk + hbase;
    const unsigned short* const vbase = Wv + (size_t)head * HD * S_LEN;

    for (int kt = 0; kt < NKT; ++kt) {
        __syncthreads();
        // ---- stage K (bf16 copy, swizzled chunks) ----
        #pragma unroll
        for (int i = 0; i < 4; ++i) {
            int row = r0k + 32 * i;
            bf16x8 kv = *(const bf16x8*)(kbase +
                (size_t)(kt * KTILE + row) * HD + kch * 8);
            *(bf16x8*)&Kl[row * KSTR + chk * 8] = kv;
        }
        // ---- stage V^T (bf16 copy; columns pre-permuted in ws) ----
        #pragma unroll
        for (int i = 0; i < 4; ++i) {
            int id = t + 256 * i;
            int d = id >> 4, ch = id & 15;
            bf16x8 vv = *(const bf16x8*)(vbase +
                (size_t)d * S_LEN + kt * KTILE + ch * 8);
            *(bf16x8*)&Vt[d * VSTR + ch * 8] = vv;
        }
        __syncthreads();

        // ---- S'^T = K.Q'^T (log2-domain scores) ----
        f32x4 sacc[8][2];
        #pragma unroll
        for (int k8 = 0; k8 < 8; ++k8)
            #pragma unroll
            for (int rt = 0; rt < 2; ++rt) sacc[k8][rt] = (f32x4){0.f,0.f,0.f,0.f};

        #pragma unroll
        for (int kd = 0; kd < 2; ++kd) {
            const int coff = (((kd << 2) + quad + m) & 7) << 3;
            #pragma unroll
            for (int k8 = 0; k8 < 8; ++k8) {
                bf16x8 kf = *(const bf16x8*)&Kl[(k8 * 16 + m) * KSTR + coff];
                sacc[k8][0] = __builtin_amdgcn_mfma_f32_16x16x32_bf16(
                    kf, qf[0][kd], sacc[k8][0], 0, 0, 0);
                sacc[k8][1] = __builtin_amdgcn_mfma_f32_16x16x32_bf16(
                    kf, qf[1][kd], sacc[k8][1], 0, 0, 0);
            }
        }

        // ---- online softmax (log2-domain) ----
        unsigned int pkv[8][2][2];
        #pragma unroll
        for (int rt = 0; rt < 2; ++rt) {
            float cm = sacc[0][rt][0];
            #pragma unroll
            for (int k8 = 0; k8 < 8; ++k8)
                #pragma unroll
                for (int r = 0; r < 4; ++r)
                    cm = fmaxf(cm, sacc[k8][rt][r]);
            cm = fmaxf(cm, __shfl_xor(cm, 16, 64));
            cm = fmaxf(cm, __shfl_xor(cm, 32, 64));

            float mo = mrow[rt];
            float mn = fmaxf(mo, cm);
            float bias = cm - mn - mn;        // p = exp2(s' + cm' - 2mn')
            mrow[rt] = mn;

            if (__any(cm > mo)) {             // wave-uniform rescale skip
                float osc = e2(mo - mn);      // exp2(-inf)=0 first tile
                #pragma unroll
                for (int dt = 0; dt < 4; ++dt) {
                    oacc[dt][rt][0] *= osc; oacc[dt][rt][1] *= osc;
                    oacc[dt][rt][2] *= osc; oacc[dt][rt][3] *= osc;
                }
                lrow[rt] *= osc;
            }

            float rs = 0.f;
            #pragma unroll
            for (int k8 = 0; k8 < 8; ++k8) {
                float p0 = e2(sacc[k8][rt][0] + bias);
                float p1 = e2(sacc[k8][rt][1] + bias);
                float p2 = e2(sacc[k8][rt][2] + bias);
                float p3 = e2(sacc[k8][rt][3] + bias);
                rs += (p0 + p1) + (p2 + p3);
                pkv[k8][rt][0] = pkt(p0, p1);
                pkv[k8][rt][1] = pkt(p2, p3);
            }
            rs += __shfl_xor(rs, 16, 64);
            rs += __shfl_xor(rs, 32, 64);
            lrow[rt] += rs;
        }

        // ---- O^T += V^T.P^T (single b128 V frags; P from registers) ----
        #pragma unroll
        for (int kc = 0; kc < 4; ++kc) {
            bf16x8 pf[2];
            #pragma unroll
            for (int rt = 0; rt < 2; ++rt) {
                union { unsigned int u[4]; bf16x8 v; } cv;
                cv.u[0] = pkv[2 * kc][rt][0];
                cv.u[1] = pkv[2 * kc][rt][1];
                cv.u[2] = pkv[2 * kc + 1][rt][0];
                cv.u[3] = pkv[2 * kc + 1][rt][1];
                pf[rt] = cv.v;
            }
            #pragma unroll
            for (int dt = 0; dt < 4; ++dt) {
                bf16x8 vf = *(const bf16x8*)&Vt[(dt * 16 + m) * VSTR +
                                                kc * 32 + quad * 8];
                oacc[dt][0] = __builtin_amdgcn_mfma_f32_16x16x32_bf16(
                    vf, pf[0], oacc[dt][0], 0, 0, 0);
                oacc[dt][1] = __builtin_amdgcn_mfma_f32_16x16x32_bf16(
                    vf, pf[1], oacc[dt][1], 0, 0, 0);
            }
        }
    }

    // ---- epilogue: O^T/l -> LDS transpose -> coalesced stores ----
    __syncthreads();
    float* Ol = (float*)smem;
    #pragma unroll
    for (int rt = 0; rt < 2; ++rt) {
        float inv = 1.0f / lrow[rt];
        #pragma unroll
        for (int dt = 0; dt < 4; ++dt)
            #pragma unroll
            for (int r = 0; r < 4; ++r)
                Ol[(wave * 32 + rt * 16 + m) * OSTR + dt * 16 + quad * 4 + r] =
                    oacc[dt][rt][r] * inv;
    }
    __syncthreads();
    const size_t obase = hbase + (size_t)(qblk * QTILE) * HD;
    #pragma unroll
    for (int s = 0; s < 8; ++s) {
        int row = s * 16 + (t >> 4);
        int col = (t & 15) * 4;
        *(float4*)&O[obase + (size_t)row * HD + col] =
            *(const float4*)&Ol[row * OSTR + col];
    }
}

// -------- fallback (round-2 kernel, used if ws too small) --------
__global__ __launch_bounds__(256, 3)
void fattn_fallback(const float* __restrict__ Q,
                    const float* __restrict__ K,
                    const float* __restrict__ V,
                    float* __restrict__ O) {
    __shared__ __align__(16) unsigned short smem[SMEM_U16];
    const int t = threadIdx.x, wave = t >> 6, lane = t & 63;
    const int m = lane & 15, quad = lane >> 4;
    const int qblk = blockIdx.x, head = blockIdx.y;
    const size_t hbase = (size_t)head * S_LEN * HD;
    unsigned short* const Kl = smem;
    unsigned short* const Vt = smem + VT_OFF;

    bf16x8 qf[2][2];
    #pragma unroll
    for (int rt = 0; rt < 2; ++rt) {
        const float* qp = Q + hbase +
            (size_t)(qblk * QTILE + wave * 32 + rt * 16 + m) * HD + quad * 8;
        #pragma unroll
        for (int kd = 0; kd < 2; ++kd) {
            float4 a = *(const float4*)(qp + kd * 32);
            float4 b = *(const float4*)(qp + kd * 32 + 4);
            union { unsigned int u[4]; bf16x8 v; } cv;
            cv.u[0] = pk2(a.x * 0.125f, a.y * 0.125f);
            cv.u[1] = pk2(a.z * 0.125f, a.w * 0.125f);
            cv.u[2] = pk2(b.x * 0.125f, b.y * 0.125f);
            cv.u[3] = pk2(b.z * 0.125f, b.w * 0.125f);
            qf[rt][kd] = cv.v;
        }
    }
    f32x4 oacc[4][2];
    float mrow[2] = {-INFINITY, -INFINITY};
    float lrow[2] = {0.f, 0.f};
    #pragma unroll
    for (int dt = 0; dt < 4; ++dt)
        #pragma unroll
        for (int rt = 0; rt < 2; ++rt) oacc[dt][rt] = (f32x4){0.f,0.f,0.f,0.f};
    const int r0k = t >> 3, c0k = (t & 7) * 8;
    const int chk = ((t & 7) + ((t >> 3) & 7)) & 7;
    const int vkey = t & 127, vdb = (t >> 7) * 32;
    unsigned short* const vwp = &Vt[vdb * VSTR + vkey];
    float4 va[4][2];
    {
        const float* vp = V + hbase + (size_t)vkey * HD + vdb;
        #pragma unroll
        for (int i = 0; i < 4; ++i) {
            va[i][0] = *(const float4*)(vp + i * 8);
            va[i][1] = *(const float4*)(vp + i * 8 + 4);
        }
    }
    for (int kt = 0; kt < NKT; ++kt) {
        __syncthreads();
        #pragma unroll
        for (int i = 0; i < 4; ++i) {
            #pragma unroll
            for (int j = 0; j < 8; ++j) {
                float f = ((const float*)&va[i][j >> 2])[j & 3];
                unsigned int u = __builtin_bit_cast(unsigned int, f) + 0x8000u;
                vwp[(i * 8 + j) * VSTR] = (unsigned short)(u >> 16);
            }
        }
        {
            const float* kp = K + hbase + (size_t)(kt * KTILE + r0k) * HD + c0k;
            #pragma unroll
            for (int i = 0; i < 4; ++i) {
                float4 a = *(const float4*)(kp + i * 32 * HD);
                float4 b = *(const float4*)(kp + i * 32 * HD + 4);
                union { unsigned int u[4]; bf16x8 v; } cv;
                cv.u[0] = pk2(a.x, a.y); cv.u[1] = pk2(a.z, a.w);
                cv.u[2] = pk2(b.x, b.y); cv.u[3] = pk2(b.z, b.w);
                *(bf16x8*)&Kl[(r0k + i * 32) * KSTR + chk * 8] = cv.v;
            }
        }
        __syncthreads();
        {
            int nk = (kt + 1 < NKT) ? kt + 1 : 0;
            const float* vp = V + hbase + (size_t)(nk * KTILE + vkey) * HD + vdb;
            #pragma unroll
            for (int i = 0; i < 4; ++i) {
                va[i][0] = *(const float4*)(vp + i * 8);
                va[i][1] = *(const float4*)(vp + i * 8 + 4);
            }
        }
        f32x4 sacc[8][2];
        #pragma unroll
        for (int k8 = 0; k8 < 8; ++k8)
            #pragma unroll
            for (int rt = 0; rt < 2; ++rt) sacc[k8][rt] = (f32x4){0.f,0.f,0.f,0.f};
        #pragma unroll
        for (int kd = 0; kd < 2; ++kd) {
            const int coff = (((kd << 2) + quad + m) & 7) << 3;
            #pragma unroll
            for (int k8 = 0; k8 < 8; ++k8) {
                bf16x8 kf = *(const bf16x8*)&Kl[(k8 * 16 + m) * KSTR + coff];
                sacc[k8][0] = __builtin_amdgcn_mfma_f32_16x16x32_bf16(
                    kf, qf[0][kd], sacc[k8][0], 0, 0, 0);
                sacc[k8][1] = __builtin_amdgcn_mfma_f32_16x16x32_bf16(
                    kf, qf[1][kd], sacc[k8][1], 0, 0, 0);
            }
        }
        unsigned int pkv[8][2][2];
        #pragma unroll
        for (int rt = 0; rt < 2; ++rt) {
            float cm = sacc[0][rt][0];
            #pragma unroll
            for (int k8 = 0; k8 < 8; ++k8)
                #pragma unroll
                for (int r = 0; r < 4; ++r) cm = fmaxf(cm, sacc[k8][rt][r]);
            cm = fmaxf(cm, __shfl_xor(cm, 16, 64));
            cm = fmaxf(cm, __shfl_xor(cm, 32, 64));
            float mo = mrow[rt], mn = fmaxf(mo, cm);
            float osc = __expf(mo - mn);
            float bias = cm - mn - mn;
            mrow[rt] = mn;
            #pragma unroll
            for (int dt = 0; dt < 4; ++dt) {
                oacc[dt][rt][0] *= osc; oacc[dt][rt][1] *= osc;
                oacc[dt][rt][2] *= osc; oacc[dt][rt][3] *= osc;
            }
            float rs = 0.f;
            #pragma unroll
            for (int k8 = 0; k8 < 8; ++k8) {
                float p0 = __expf(sacc[k8][rt][0] + bias);
                float p1 = __expf(sacc[k8][rt][1] + bias);
                float p2 = __expf(sacc[k8][rt][2] + bias);
                float p3 = __expf(sacc[k8][rt][3] + bias);
                rs += (p0 + p1) + (p2 + p3);
                pkv[k8][rt][0] = pk2(p0, p1);
                pkv[k8][rt][1] = pk2(p2, p3);
            }
            rs += __shfl_xor(rs, 16, 64);
            rs += __shfl_xor(rs, 32, 64);
            lrow[rt] = lrow[rt] * osc + rs;
        }
        #pragma unroll
        for (int kc = 0; kc < 4; ++kc) {
            bf16x8 pf[2];
            #pragma unroll
            for (int rt = 0; rt < 2; ++rt) {
                union { unsigned int u[4]; bf16x8 v; } cv;
                cv.u[0] = pkv[2 * kc][rt][0];
                cv.u[1] = pkv[2 * kc][rt][1];
                cv.u[2] = pkv[2 * kc + 1][rt][0];
                cv.u[3] = pkv[2 * kc + 1][rt][1];
                pf[rt] = cv.v;
            }
            #pragma unroll
            for (int dt = 0; dt < 4; ++dt) {
                const unsigned short* vp0 =
                    &Vt[(dt * 16 + m) * VSTR + kc * 32 + quad * 4];
                bf16x8 vf;
                #pragma unroll
                for (int j = 0; j < 4; ++j) { vf[j] = vp0[j]; vf[4 + j] = vp0[16 + j]; }
                oacc[dt][0] = __builtin_amdgcn_mfma_f32_16x16x32_bf16(
                    vf, pf[0], oacc[dt][0], 0, 0, 0);
                oacc[dt][1] = __builtin_amdgcn_mfma_f32_16x16x32_bf16(
                    vf, pf[1], oacc[dt][1], 0, 0, 0);
            }
        }
    }
    __syncthreads();
    float* Ol = (float*)smem;
    #pragma unroll
    for (int rt = 0; rt < 2; ++rt) {
        float inv = 1.0f / lrow[rt];
        #pragma unroll
        for (int dt = 0; dt < 4; ++dt)
            #pragma unroll
            for (int r = 0; r < 4; ++r)
                Ol[(wave * 32 + rt * 16 + m) * OSTR + dt * 16 + quad * 4 + r] =
                    oacc[dt][rt][r] * inv;
    }
    __syncthreads();
    const size_t obase = hbase + (size_t)(qblk * QTILE) * HD;
    #pragma unroll
    for (int s = 0; s < 8; ++s) {
        int row = s * 16 + (t >> 4);
        int col = (t & 15) * 4;
        *(float4*)&O[obase + (size_t)row * HD + col] =
            *(const float4*)&Ol[row * OSTR + col];
    }
}

extern "C" void kernel_launch(void* const* d_in, const int* in_sizes, int n_in,
                              void* d_out, int out_size, void* d_ws, size_t ws_size,
                              hipStream_t stream) {
    (void)in_sizes; (void)n_in; (void)out_size;
    const float* Q = (const float*)d_in[0];
    const float* K = (const float*)d_in[1];
    const float* V = (const float*)d_in[2];
    float* O = (float*)d_out;
    const size_t need = 2 * WS_ELEMS * sizeof(unsigned short);   // ~50.3 MB
    if (ws_size >= need) {
        unsigned short* Wk = (unsigned short*)d_ws;
        unsigned short* Wv = Wk + WS_ELEMS;
        k_convert<<<dim3((unsigned)(WS_ELEMS / (256 * 8))), 256, 0, stream>>>(K, Wk);
        v_trans<<<dim3(NKT, NHEAD), 256, 0, stream>>>(V, Wv);
        fattn_fast<<<dim3(S_LEN / QTILE, NHEAD), 256, 0, stream>>>(Q, Wk, Wv, O);
    } else {
        fattn_fallback<<<dim3(S_LEN / QTILE, NHEAD), 256, 0, stream>>>(Q, K, V, O);
    }
}

// Round 4
// 564.945 us; speedup vs baseline: 1.6121x; 1.6121x over previous
//
#include <hip/hip_runtime.h>
#include <hip/hip_bf16.h>

// FlashAttention fwd: B=4,H=12,S=4096,D=64 fp32, reference semantics incl. the
// extra cur_scale factor, in log2-domain: p = exp2(s' + cm' - 2*mn'),
// s' = s*log2(e) (log2e folded into Q pre-scale).
// Single kernel (NO d_ws: harness re-poisons ws every iter -> cache flush tax).
// S computed transposed (S^T = K.Q^T) so P stays in registers; row-sum l is
// accumulated as a 65th output row via an all-ones MFMA A-fragment so it
// shares oacc's rescale chain exactly.

#define S_LEN 4096
#define HD    64
#define QTILE 128
#define KTILE 128
#define NKT   32

#define KSTR  72                    // u16 stride of K_lds rows (144 B)
#define VSTR  136                   // u16 stride of Vt rows (272 B)
#define VT_OFF (128 * KSTR)         // 9216 u16
#define SMEM_U16 (VT_OFF + HD * VSTR)  // 17920 u16 = 35840 B
#define OSTR  68                    // epilogue float stride (needs >= 65)

typedef __attribute__((ext_vector_type(8))) short bf16x8;
typedef __attribute__((ext_vector_type(4))) short bf16x4;
typedef __attribute__((ext_vector_type(4))) float f32x4;

// RNE f32->bf16 pair packed into u32 (staging/Q)
__device__ __forceinline__ unsigned int pk2(float f0, float f1) {
    unsigned int u0 = __builtin_bit_cast(unsigned int, f0);
    unsigned int u1 = __builtin_bit_cast(unsigned int, f1);
    u0 += 0x7FFFu + ((u0 >> 16) & 1u);
    u1 += 0x7FFFu + ((u1 >> 16) & 1u);
    return __builtin_amdgcn_perm(u1, u0, 0x07060302u);
}
// truncating pack (P only; P>=0, validated r3): 1 instr
__device__ __forceinline__ unsigned int pkt(float f0, float f1) {
    return __builtin_amdgcn_perm(__builtin_bit_cast(unsigned int, f1),
                                 __builtin_bit_cast(unsigned int, f0),
                                 0x07060302u);
}
__device__ __forceinline__ float e2(float x) {
#if __has_builtin(__builtin_amdgcn_exp2f)
    return __builtin_amdgcn_exp2f(x);
#else
    return __expf(x * 0.6931471805599453f);
#endif
}
__device__ __forceinline__ float rcp(float x) {
#if __has_builtin(__builtin_amdgcn_rcpf)
    return __builtin_amdgcn_rcpf(x);
#else
    return 1.0f / x;
#endif
}

__global__ __launch_bounds__(256, 3)
void fattn_kernel(const float* __restrict__ Q,
                  const float* __restrict__ K,
                  const float* __restrict__ V,
                  float* __restrict__ O) {
    __shared__ __align__(16) unsigned short smem[SMEM_U16];

    const int t    = threadIdx.x;
    const int wave = t >> 6;
    const int lane = t & 63;
    const int m    = lane & 15;
    const int quad = lane >> 4;

    const int qblk = blockIdx.x;
    const int head = blockIdx.y;
    const size_t hbase = (size_t)head * S_LEN * HD;

    unsigned short* const Kl = smem;
    unsigned short* const Vt = smem + VT_OFF;

    // ---- Q B-frags; scale = 0.125*log2(e) (log2-domain scores) ----
    bf16x8 qf[2][2];
    #pragma unroll
    for (int rt = 0; rt < 2; ++rt) {
        const float* qp = Q + hbase +
            (size_t)(qblk * QTILE + wave * 32 + rt * 16 + m) * HD + quad * 8;
        #pragma unroll
        for (int kd = 0; kd < 2; ++kd) {
            float4 a = *(const float4*)(qp + kd * 32);
            float4 b = *(const float4*)(qp + kd * 32 + 4);
            union { unsigned int u[4]; bf16x8 v; } cv;
            const float s = 0.1803368801111f;   // 0.125 * log2(e)
            cv.u[0] = pk2(a.x * s, a.y * s);
            cv.u[1] = pk2(a.z * s, a.w * s);
            cv.u[2] = pk2(b.x * s, b.y * s);
            cv.u[3] = pk2(b.z * s, b.w * s);
            qf[rt][kd] = cv.v;
        }
    }

    // ones A-frag: row 0 of A all 1.0bf16 -> D row0 = column sums of P
    bf16x8 ones;
    {
        unsigned int oo = (m == 0) ? 0x3F803F80u : 0u;
        union { unsigned int u[4]; bf16x8 v; } cv;
        cv.u[0] = oo; cv.u[1] = oo; cv.u[2] = oo; cv.u[3] = oo;
        ones = cv.v;
    }

    f32x4 oacc[4][2];                // O^T[d-tile][rt]
    f32x4 lacc[2];                   // l as extra MFMA row (reg0/quad0 valid)
    float mrow[2] = {-INFINITY, -INFINITY};
    #pragma unroll
    for (int dt = 0; dt < 4; ++dt)
        #pragma unroll
        for (int rt = 0; rt < 2; ++rt) oacc[dt][rt] = (f32x4){0.f,0.f,0.f,0.f};
    lacc[0] = (f32x4){0.f,0.f,0.f,0.f};
    lacc[1] = (f32x4){0.f,0.f,0.f,0.f};

    // ---- staging maps & hoisted LDS bases (all kt-invariant) ----
    const int r0k = t >> 3;                         // K: row
    const int c0k = (t & 7) * 8;                    // K: global col
    const int chk = ((t & 7) + ((t >> 3) & 7)) & 7; // K: swizzled chunk
    const int vp_ = t & 63;                         // V: key pair (2p,2p+1)
    const int vd0 = (t >> 6) * 16;                  // V: d-range base
    unsigned short* const kwb = &Kl[r0k * KSTR + chk * 8];
    unsigned short* const vwb = &Vt[vd0 * VSTR + 2 * vp_];
    const unsigned short* const kb0 = &Kl[m * KSTR + (((quad + m) & 7) << 3)];
    const unsigned short* const kb1 = &Kl[m * KSTR + (((4 + quad + m) & 7) << 3)];
    const unsigned short* const vrb = &Vt[m * VSTR + quad * 4];

    // ---- initial V prefetch (tile 0): 2 keys x 16 floats ----
    float4 va[2][4];
    {
        const float* vp = V + hbase + (size_t)(2 * vp_) * HD + vd0;
        #pragma unroll
        for (int e = 0; e < 2; ++e)
            #pragma unroll
            for (int j = 0; j < 4; ++j)
                va[e][j] = *(const float4*)(vp + e * HD + j * 4);
    }

    for (int kt = 0; kt < NKT; ++kt) {
        __syncthreads();   // previous tile's LDS reads done

        // ---- V regs -> Vt (transposed, b32 pair-packed writes) ----
        #pragma unroll
        for (int d = 0; d < 16; ++d) {
            float f0 = ((const float*)&va[0][0])[d];
            float f1 = ((const float*)&va[1][0])[d];
            *(unsigned int*)(vwb + d * VSTR) = pk2(f0, f1);
        }
        // ---- stage K tile kt (b128 writes, swizzled chunks) ----
        {
            const float* kp = K + hbase + (size_t)(kt * KTILE + r0k) * HD + c0k;
            #pragma unroll
            for (int i = 0; i < 4; ++i) {
                float4 a = *(const float4*)(kp + i * 32 * HD);
                float4 b = *(const float4*)(kp + i * 32 * HD + 4);
                union { unsigned int u[4]; bf16x8 v; } cv;
                cv.u[0] = pk2(a.x, a.y); cv.u[1] = pk2(a.z, a.w);
                cv.u[2] = pk2(b.x, b.y); cv.u[3] = pk2(b.z, b.w);
                *(bf16x8*)(kwb + i * 32 * KSTR) = cv.v;
            }
        }
        __syncthreads();   // staging visible

        // ---- prefetch next tile's V (hidden behind compute) ----
        {
            int nk = (kt + 1 < NKT) ? kt + 1 : 0;
            const float* vp = V + hbase + (size_t)(nk * KTILE + 2 * vp_) * HD + vd0;
            #pragma unroll
            for (int e = 0; e < 2; ++e)
                #pragma unroll
                for (int j = 0; j < 4; ++j)
                    va[e][j] = *(const float4*)(vp + e * HD + j * 4);
        }

        // ---- S'^T = K.Q'^T (log2-domain) ----
        f32x4 sacc[8][2];
        #pragma unroll
        for (int k8 = 0; k8 < 8; ++k8)
            #pragma unroll
            for (int rt = 0; rt < 2; ++rt) sacc[k8][rt] = (f32x4){0.f,0.f,0.f,0.f};

        #pragma unroll
        for (int k8 = 0; k8 < 8; ++k8) {
            bf16x8 kf0 = *(const bf16x8*)(kb0 + k8 * 16 * KSTR);
            bf16x8 kf1 = *(const bf16x8*)(kb1 + k8 * 16 * KSTR);
            sacc[k8][0] = __builtin_amdgcn_mfma_f32_16x16x32_bf16(
                kf0, qf[0][0], sacc[k8][0], 0, 0, 0);
            sacc[k8][1] = __builtin_amdgcn_mfma_f32_16x16x32_bf16(
                kf0, qf[1][0], sacc[k8][1], 0, 0, 0);
            sacc[k8][0] = __builtin_amdgcn_mfma_f32_16x16x32_bf16(
                kf1, qf[0][1], sacc[k8][0], 0, 0, 0);
            sacc[k8][1] = __builtin_amdgcn_mfma_f32_16x16x32_bf16(
                kf1, qf[1][1], sacc[k8][1], 0, 0, 0);
        }

        // ---- online softmax (log2-domain); l handled by MFMA ones-row ----
        unsigned int pkv[8][2][2];
        #pragma unroll
        for (int rt = 0; rt < 2; ++rt) {
            float cm = fmaxf(fmaxf(sacc[0][rt][0], sacc[0][rt][1]),
                             fmaxf(sacc[0][rt][2], sacc[0][rt][3]));
            #pragma unroll
            for (int k8 = 1; k8 < 8; ++k8) {
                float a = fmaxf(sacc[k8][rt][0], sacc[k8][rt][1]);
                float b = fmaxf(sacc[k8][rt][2], sacc[k8][rt][3]);
                cm = fmaxf(cm, fmaxf(a, b));
            }
            cm = fmaxf(cm, __shfl_xor(cm, 16, 64));
            cm = fmaxf(cm, __shfl_xor(cm, 32, 64));

            float mo = mrow[rt];
            float mn = fmaxf(mo, cm);
            float bias = cm - mn - mn;        // p = exp2(s' + cm' - 2mn')
            mrow[rt] = mn;

            if (__any(cm > mo)) {             // wave-uniform rescale skip
                float osc = e2(mo - mn);      // exp2(-inf)=0 on first tile
                #pragma unroll
                for (int dt = 0; dt < 4; ++dt) {
                    oacc[dt][rt][0] *= osc; oacc[dt][rt][1] *= osc;
                    oacc[dt][rt][2] *= osc; oacc[dt][rt][3] *= osc;
                }
                lacc[rt][0] *= osc;           // only row0 (reg0) meaningful
            }

            #pragma unroll
            for (int k8 = 0; k8 < 8; ++k8) {
                float p0 = e2(sacc[k8][rt][0] + bias);
                float p1 = e2(sacc[k8][rt][1] + bias);
                float p2 = e2(sacc[k8][rt][2] + bias);
                float p3 = e2(sacc[k8][rt][3] + bias);
                pkv[k8][rt][0] = pkt(p0, p1);
                pkv[k8][rt][1] = pkt(p2, p3);
            }
        }

        // ---- O^T += V^T.P^T ; l-row += 1.P^T ----
        #pragma unroll
        for (int kc = 0; kc < 4; ++kc) {
            bf16x8 pf[2];
            #pragma unroll
            for (int rt = 0; rt < 2; ++rt) {
                union { unsigned int u[4]; bf16x8 v; } cv;
                cv.u[0] = pkv[2 * kc][rt][0];
                cv.u[1] = pkv[2 * kc][rt][1];
                cv.u[2] = pkv[2 * kc + 1][rt][0];
                cv.u[3] = pkv[2 * kc + 1][rt][1];
                pf[rt] = cv.v;
            }
            #pragma unroll
            for (int dt = 0; dt < 4; ++dt) {
                union { struct { bf16x4 lo, hi; } s; bf16x8 v; } uf;
                uf.s.lo = *(const bf16x4*)(vrb + dt * 16 * VSTR + kc * 32);
                uf.s.hi = *(const bf16x4*)(vrb + dt * 16 * VSTR + kc * 32 + 16);
                oacc[dt][0] = __builtin_amdgcn_mfma_f32_16x16x32_bf16(
                    uf.v, pf[0], oacc[dt][0], 0, 0, 0);
                oacc[dt][1] = __builtin_amdgcn_mfma_f32_16x16x32_bf16(
                    uf.v, pf[1], oacc[dt][1], 0, 0, 0);
            }
            lacc[0] = __builtin_amdgcn_mfma_f32_16x16x32_bf16(
                ones, pf[0], lacc[0], 0, 0, 0);
            lacc[1] = __builtin_amdgcn_mfma_f32_16x16x32_bf16(
                ones, pf[1], lacc[1], 0, 0, 0);
        }
    }

    // ---- epilogue: LDS transpose (O rows + l column), divide, store ----
    __syncthreads();
    float* Ol = (float*)smem;
    #pragma unroll
    for (int rt = 0; rt < 2; ++rt) {
        #pragma unroll
        for (int dt = 0; dt < 4; ++dt)
            #pragma unroll
            for (int r = 0; r < 4; ++r)
                Ol[(wave * 32 + rt * 16 + m) * OSTR + dt * 16 + quad * 4 + r] =
                    oacc[dt][rt][r];
        if (quad == 0)
            Ol[(wave * 32 + rt * 16 + m) * OSTR + 64] = lacc[rt][0];
    }
    __syncthreads();
    const size_t obase = hbase + (size_t)(qblk * QTILE) * HD;
    #pragma unroll
    for (int s = 0; s < 8; ++s) {
        int row = s * 16 + (t >> 4);
        int col = (t & 15) * 4;
        float inv = rcp(Ol[row * OSTR + 64]);
        const float* src = &Ol[row * OSTR + col];
        float4 o;
        o.x = src[0] * inv; o.y = src[1] * inv;
        o.z = src[2] * inv; o.w = src[3] * inv;
        *(float4*)&O[obase + (size_t)row * HD + col] = o;
    }
}

extern "C" void kernel_launch(void* const* d_in, const int* in_sizes, int n_in,
                              void* d_out, int out_size, void* d_ws, size_t ws_size,
                              hipStream_t stream) {
    (void)in_sizes; (void)n_in; (void)d_ws; (void)ws_size; (void)out_size;
    const float* Q = (const float*)d_in[0];
    const float* K = (const float*)d_in[1];
    const float* V = (const float*)d_in[2];
    float* O = (float*)d_out;
    dim3 grid(S_LEN / QTILE, 4 * 12);
    fattn_kernel<<<grid, 256, 0, stream>>>(Q, K, V, O);
}